// Round 2
// baseline (630.080 us; speedup 1.0000x reference)
//
#include <hip/hip_runtime.h>

typedef __attribute__((ext_vector_type(4))) float f32x4;
typedef __attribute__((ext_vector_type(8))) short s16x8;

static __device__ __forceinline__ unsigned short f2bf(float f){
  unsigned int u = __builtin_bit_cast(unsigned int, f);
  u = (u + 0x7fffu + ((u >> 16) & 1u)) >> 16;
  return (unsigned short)u;
}
static __device__ __forceinline__ float bf2f(unsigned short s){
  unsigned int u = ((unsigned int)s) << 16;
  return __builtin_bit_cast(float, u);
}
static __device__ __forceinline__ float tanh_fast(float x){
  float ex = __expf(2.0f * x);                       // inf for big x -> still correct below
  return 1.0f - 2.0f * __builtin_amdgcn_rcpf(ex + 1.0f);
}

// ---------------- prep: BN fold + MFMA B-fragment packing (bf16) ----------------
// B-frag layout for mfma_f32_16x16x32_bf16: lane l supplies B[k=(l>>4)*8+i][col=n0*16+(l&15)]
// packed flat index: ((tile)*64 + lane)*8 + i
__global__ void prep_kernel(const float* __restrict__ W1, const float* __restrict__ W2,
                            const float* __restrict__ W3, const float* __restrict__ b2,
                            const float* __restrict__ g, const float* __restrict__ be,
                            const float* __restrict__ mn, const float* __restrict__ vr,
                            unsigned short* __restrict__ w1p, unsigned short* __restrict__ w2cp,
                            unsigned short* __restrict__ w3p, float* __restrict__ bnsc,
                            float* __restrict__ bnsh)
{
  int t = blockIdx.x * blockDim.x + threadIdx.x;
  int nt = gridDim.x * blockDim.x;
  for (int idx = t; idx < 4096; idx += nt){
    int i = idx & 7, lane = (idx >> 3) & 63, n0 = idx >> 9;
    w1p[idx] = f2bf(W1[((lane >> 4) * 8 + i) * 128 + n0 * 16 + (lane & 15)]);
  }
  for (int idx = t; idx < 16384; idx += nt){
    int i = idx & 7, lane = (idx >> 3) & 63, n0 = (idx >> 9) & 7, kk = idx >> 12;
    int k = kk * 32 + (lane >> 4) * 8 + i;
    int j = n0 * 16 + (lane & 15);
    w2cp[idx] = f2bf(W2[(size_t)(256 + k) * 128 + j]);   // W2c = rows 256..383
    w3p[idx]  = f2bf(W3[(size_t)k * 128 + j]);
  }
  for (int idx = t; idx < 128; idx += nt){
    float sc = g[idx] * rsqrtf(vr[idx] + 1e-5f);
    bnsc[idx] = sc;
    bnsh[idx] = (b2[idx] - mn[idx]) * sc + be[idx];      // fold b2 into BN shift
  }
}

// ---------------- node GEMM: P = x@W2[0:128], Q = x@W2[128:256], f32, bf16 out ----------------
__global__ __launch_bounds__(256) void node_kernel(
    const float* __restrict__ x, const float* __restrict__ W2,
    unsigned short* __restrict__ P, unsigned short* __restrict__ Q, int N)
{
  __shared__ __align__(16) float xs[32 * 132];
  __shared__ __align__(16) float wsm[32 * 256];
  const int tid = threadIdx.x;
  const int nb = blockIdx.x * 32;
  #pragma unroll
  for (int i = 0; i < 4; i++){
    int idx = i * 1024 + tid * 4;
    int row = idx >> 7, col = idx & 127;
    int n = nb + row; if (n >= N) n = N - 1;
    *(f32x4*)&xs[row * 132 + col] = *(const f32x4*)&x[(size_t)n * 128 + col];
  }
  float acc[32];
  #pragma unroll
  for (int a = 0; a < 32; a++) acc[a] = 0.f;
  const int jg = tid & 7, nl = tid >> 3;
  for (int kc = 0; kc < 4; kc++){
    __syncthreads();
    #pragma unroll
    for (int i = 0; i < 8; i++){
      int idx = i * 1024 + tid * 4;
      int k = idx >> 8, j = idx & 255;
      const float* src = (j < 128) ? &W2[(size_t)(kc * 32 + k) * 128 + j]
                                   : &W2[(size_t)(128 + kc * 32 + k) * 128 + (j - 128)];
      *(f32x4*)&wsm[k * 256 + j] = *(const f32x4*)src;
    }
    __syncthreads();
    #pragma unroll 8
    for (int k = 0; k < 32; k++){
      float xv = xs[nl * 132 + kc * 32 + k];
      #pragma unroll
      for (int q = 0; q < 4; q++){
        f32x4 wp = *(const f32x4*)&wsm[k * 256 + jg * 4 + q * 32];
        f32x4 wq = *(const f32x4*)&wsm[k * 256 + 128 + jg * 4 + q * 32];
        #pragma unroll
        for (int ii = 0; ii < 4; ii++){
          acc[q * 4 + ii]      = fmaf(xv, wp[ii], acc[q * 4 + ii]);
          acc[16 + q * 4 + ii] = fmaf(xv, wq[ii], acc[16 + q * 4 + ii]);
        }
      }
    }
  }
  const int n = nb + nl;
  if (n < N){
    #pragma unroll
    for (int q = 0; q < 4; q++){
      uint2 v;
      v.x = (unsigned int)f2bf(acc[q*4+0]) | ((unsigned int)f2bf(acc[q*4+1]) << 16);
      v.y = (unsigned int)f2bf(acc[q*4+2]) | ((unsigned int)f2bf(acc[q*4+3]) << 16);
      *(uint2*)&P[(size_t)n * 128 + jg * 4 + q * 32] = v;
      v.x = (unsigned int)f2bf(acc[16+q*4+0]) | ((unsigned int)f2bf(acc[16+q*4+1]) << 16);
      v.y = (unsigned int)f2bf(acc[16+q*4+2]) | ((unsigned int)f2bf(acc[16+q*4+3]) << 16);
      *(uint2*)&Q[(size_t)n * 128 + jg * 4 + q * 32] = v;
    }
  }
}

// ---------------- fused edge kernel: 4 waves x 32 edges, MFMA chain ----------------
__global__ __launch_bounds__(256) void edge_kernel(
    const float* __restrict__ ea, const int* __restrict__ eidx,
    const unsigned short* __restrict__ P, const unsigned short* __restrict__ Q,
    const unsigned short* __restrict__ w1p, const unsigned short* __restrict__ w2cp,
    const unsigned short* __restrict__ w3p,
    const float* __restrict__ b1, const float* __restrict__ b3,
    const float* __restrict__ bnsc, const float* __restrict__ bnsh,
    float* __restrict__ y, int E, int N)
{
  __shared__ __align__(16) unsigned short w1f[4096];      // 8 KB
  __shared__ __align__(16) unsigned short w2cf[16384];    // 32 KB
  __shared__ __align__(16) unsigned short tch[4][32 * 40];// 10 KB (padded rows: 40 bf16 = 80B, 16B-aligned)
  __shared__ float cb1[128], cb3[128], cbs[128], cbh[128];

  const int tid = threadIdx.x;
  {
    const uint4* s1 = (const uint4*)w1p; uint4* d1 = (uint4*)w1f;
    d1[tid] = s1[tid];
    d1[tid + 256] = s1[tid + 256];
    const uint4* s2 = (const uint4*)w2cp; uint4* d2 = (uint4*)w2cf;
    #pragma unroll
    for (int i = 0; i < 8; i++) d2[tid + i * 256] = s2[tid + i * 256];
    if (tid < 128){ cb1[tid] = b1[tid]; cb3[tid] = b3[tid]; cbs[tid] = bnsc[tid]; cbh[tid] = bnsh[tid]; }
  }
  __syncthreads();

  const int wid = tid >> 6, lane = tid & 63;
  const int r16 = lane & 15, hi = lane >> 4;
  const int e0 = (blockIdx.x * 4 + wid) * 32;
  unsigned short* myt = &tch[wid][0];

  // A-fragments of edge_attr (row = l&15 -> edge, k = (l>>4)*8+i)
  s16x8 aF[2];
  #pragma unroll
  for (int m = 0; m < 2; m++){
    int e = e0 + m * 16 + r16; if (e >= E) e = E - 1;
    const f32x4* p = (const f32x4*)(ea + (size_t)e * 32 + hi * 8);
    f32x4 v0 = p[0], v1 = p[1];
    s16x8 t;
    t[0] = (short)f2bf(v0[0]); t[1] = (short)f2bf(v0[1]); t[2] = (short)f2bf(v0[2]); t[3] = (short)f2bf(v0[3]);
    t[4] = (short)f2bf(v1[0]); t[5] = (short)f2bf(v1[1]); t[6] = (short)f2bf(v1[2]); t[7] = (short)f2bf(v1[3]);
    aF[m] = t;
  }

  const s16x8* w1fv = (const s16x8*)w1f;
  const s16x8* w2cfv = (const s16x8*)w2cf;
  const f32x4 z = {0.f, 0.f, 0.f, 0.f};

  f32x4 c2[2][8];
  #pragma unroll
  for (int m = 0; m < 2; m++)
    #pragma unroll
    for (int n0 = 0; n0 < 8; n0++) c2[m][n0] = z;

  // S1 (ea@W1 -> tanh -> t) chunked by K, feeding S2 (t@W2c) through LDS transpose
  #pragma unroll
  for (int kk = 0; kk < 4; kk++){
    f32x4 t1[2][2];
    #pragma unroll
    for (int j2 = 0; j2 < 2; j2++){
      s16x8 bF = w1fv[(kk * 2 + j2) * 64 + lane];
      t1[0][j2] = __builtin_amdgcn_mfma_f32_16x16x32_bf16(aF[0], bF, z, 0, 0, 0);
      t1[1][j2] = __builtin_amdgcn_mfma_f32_16x16x32_bf16(aF[1], bF, z, 0, 0, 0);
    }
    #pragma unroll
    for (int j2 = 0; j2 < 2; j2++){
      const int n0t = kk * 2 + j2;
      const float bb = cb1[n0t * 16 + r16];
      #pragma unroll
      for (int m = 0; m < 2; m++){
        #pragma unroll
        for (int r = 0; r < 4; r++){
          // C layout: row=(l>>4)*4+r (edge), col=l&15 (+16*n0t)
          float tv = tanh_fast(t1[m][j2][r] + bb);
          myt[(m * 16 + hi * 4 + r) * 40 + j2 * 16 + r16] = f2bf(tv);
        }
      }
    }
    s16x8 a2[2];
    #pragma unroll
    for (int m = 0; m < 2; m++)
      a2[m] = *(const s16x8*)(myt + (m * 16 + r16) * 40 + hi * 8);
    #pragma unroll
    for (int n0 = 0; n0 < 8; n0++){
      s16x8 bF = w2cfv[(kk * 8 + n0) * 64 + lane];
      c2[0][n0] = __builtin_amdgcn_mfma_f32_16x16x32_bf16(a2[0], bF, c2[0][n0], 0, 0, 0);
      c2[1][n0] = __builtin_amdgcn_mfma_f32_16x16x32_bf16(a2[1], bF, c2[1][n0], 0, 0, 0);
    }
  }

  // gather indices for this lane's 8 edges
  int rowi[2][4], coli[2][4];
  #pragma unroll
  for (int m = 0; m < 2; m++){
    #pragma unroll
    for (int r = 0; r < 4; r++){
      int em = e0 + m * 16 + hi * 4 + r; if (em >= E) em = E - 1;
      int ri = eidx[em];     ri = (ri < 0) ? 0 : (ri >= N ? N - 1 : ri);
      int ci = eidx[E + em]; ci = (ci < 0) ? 0 : (ci >= N ? N - 1 : ci);
      rowi[m][r] = ri; coli[m][r] = ci;
    }
  }

  // epilogue (P[row]+Q[col]+BN+ReLU) chunked, feeding S3 (h@W3) through LDS transpose
  f32x4 c3[2][8];
  #pragma unroll
  for (int m = 0; m < 2; m++)
    #pragma unroll
    for (int n0 = 0; n0 < 8; n0++) c3[m][n0] = z;

  const uint4* w3g = (const uint4*)w3p;
  #pragma unroll
  for (int kk = 0; kk < 4; kk++){
    #pragma unroll
    for (int j2 = 0; j2 < 2; j2++){
      const int n0 = kk * 2 + j2;
      const float sc = cbs[n0 * 16 + r16], sh = cbh[n0 * 16 + r16];
      #pragma unroll
      for (int m = 0; m < 2; m++){
        #pragma unroll
        for (int r = 0; r < 4; r++){
          float hv = c2[m][n0][r]
            + bf2f(P[(size_t)rowi[m][r] * 128 + n0 * 16 + r16])
            + bf2f(Q[(size_t)coli[m][r] * 128 + n0 * 16 + r16]);
          hv = fmaf(hv, sc, sh);
          hv = fmaxf(hv, 0.0f);
          myt[(m * 16 + hi * 4 + r) * 40 + j2 * 16 + r16] = f2bf(hv);
        }
      }
    }
    s16x8 a3[2];
    #pragma unroll
    for (int m = 0; m < 2; m++)
      a3[m] = *(const s16x8*)(myt + (m * 16 + r16) * 40 + hi * 8);
    #pragma unroll
    for (int n0 = 0; n0 < 8; n0++){
      uint4 bu = w3g[(kk * 8 + n0) * 64 + lane];
      union { uint4 u; s16x8 s; } cv; cv.u = bu;
      c3[0][n0] = __builtin_amdgcn_mfma_f32_16x16x32_bf16(a3[0], cv.s, c3[0][n0], 0, 0, 0);
      c3[1][n0] = __builtin_amdgcn_mfma_f32_16x16x32_bf16(a3[1], cv.s, c3[1][n0], 0, 0, 0);
    }
  }

  // y = relu(c3 + b3), coalesced 64B chunks per 16-lane group
  #pragma unroll
  for (int m = 0; m < 2; m++){
    #pragma unroll
    for (int r = 0; r < 4; r++){
      int em = e0 + m * 16 + hi * 4 + r;
      if (em < E){
        float* yp = y + (size_t)em * 128 + r16;
        #pragma unroll
        for (int n0 = 0; n0 < 8; n0++)
          yp[n0 * 16] = fmaxf(c3[m][n0][r] + cb3[n0 * 16 + r16], 0.0f);
      }
    }
  }
}

extern "C" void kernel_launch(void* const* d_in, const int* in_sizes, int n_in,
                              void* d_out, int out_size, void* d_ws, size_t ws_size,
                              hipStream_t stream)
{
  const float* x    = (const float*)d_in[0];
  const int*   eidx = (const int*)d_in[1];
  const float* ea   = (const float*)d_in[2];
  const float* W1   = (const float*)d_in[3];
  const float* b1   = (const float*)d_in[4];
  const float* W2   = (const float*)d_in[5];
  const float* b2   = (const float*)d_in[6];
  const float* bng  = (const float*)d_in[7];
  const float* bnb  = (const float*)d_in[8];
  const float* bnm  = (const float*)d_in[9];
  const float* bnv  = (const float*)d_in[10];
  const float* W3   = (const float*)d_in[11];
  const float* b3   = (const float*)d_in[12];
  float* y = (float*)d_out;
  const int N = in_sizes[0] / 128;
  const int E = in_sizes[2] / 32;

  // ws layout: P bf16 [N*128] | Q bf16 [N*128] | w1p[4096] | w2cp[16384] | w3p[16384] | bnsc[128] | bnsh[128]
  unsigned short* P    = (unsigned short*)d_ws;
  unsigned short* Qq   = P + (size_t)N * 128;
  unsigned short* w1p  = Qq + (size_t)N * 128;
  unsigned short* w2cp = w1p + 4096;
  unsigned short* w3p  = w2cp + 16384;
  float* bnsc = (float*)(w3p + 16384);
  float* bnsh = bnsc + 128;

  hipLaunchKernelGGL(prep_kernel, dim3(64), dim3(256), 0, stream,
                     W1, W2, W3, b2, bng, bnb, bnm, bnv, w1p, w2cp, w3p, bnsc, bnsh);
  hipLaunchKernelGGL(node_kernel, dim3((N + 31) / 32), dim3(256), 0, stream, x, W2, P, Qq, N);
  hipLaunchKernelGGL(edge_kernel, dim3((E + 127) / 128), dim3(256), 0, stream,
                     ea, eidx, P, Qq, w1p, w2cp, w3p, b1, b3, bnsc, bnsh, y, E, N);
}

// Round 4
// 566.468 us; speedup vs baseline: 1.1123x; 1.1123x over previous
//
#include <hip/hip_runtime.h>

typedef __attribute__((ext_vector_type(4))) float f32x4;
typedef __attribute__((ext_vector_type(8))) short s16x8;

static __device__ __forceinline__ unsigned short f2bf(float f){
  unsigned int u = __builtin_bit_cast(unsigned int, f);
  u = (u + 0x7fffu + ((u >> 16) & 1u)) >> 16;
  return (unsigned short)u;
}
static __device__ __forceinline__ float bf2f(unsigned short s){
  unsigned int u = ((unsigned int)s) << 16;
  return __builtin_bit_cast(float, u);
}
static __device__ __forceinline__ float tanh_fast(float x){
  float ex = __expf(2.0f * x);
  return 1.0f - 2.0f * __builtin_amdgcn_rcpf(ex + 1.0f);
}

// ---------------- prep: BN fold + MFMA B-fragment packing (bf16) ----------------
// B-frag layout for mfma_f32_16x16x32_bf16: lane l supplies B[k=(l>>4)*8+i][col=n0*16+(l&15)]
// packed flat index: ((tile)*64 + lane)*8 + i
__global__ void prep_kernel(const float* __restrict__ W1, const float* __restrict__ W2,
                            const float* __restrict__ W3, const float* __restrict__ b2,
                            const float* __restrict__ g, const float* __restrict__ be,
                            const float* __restrict__ mn, const float* __restrict__ vr,
                            unsigned short* __restrict__ w1p, unsigned short* __restrict__ w2cp,
                            unsigned short* __restrict__ w3p, float* __restrict__ bnsc,
                            float* __restrict__ bnsh)
{
  int t = blockIdx.x * blockDim.x + threadIdx.x;
  int nt = gridDim.x * blockDim.x;
  for (int idx = t; idx < 4096; idx += nt){
    int i = idx & 7, lane = (idx >> 3) & 63, n0 = idx >> 9;
    w1p[idx] = f2bf(W1[((lane >> 4) * 8 + i) * 128 + n0 * 16 + (lane & 15)]);
  }
  for (int idx = t; idx < 16384; idx += nt){
    int i = idx & 7, lane = (idx >> 3) & 63, n0 = (idx >> 9) & 7, kk = idx >> 12;
    int k = kk * 32 + (lane >> 4) * 8 + i;
    int j = n0 * 16 + (lane & 15);
    w2cp[idx] = f2bf(W2[(size_t)(256 + k) * 128 + j]);   // W2c = rows 256..383
    w3p[idx]  = f2bf(W3[(size_t)k * 128 + j]);
  }
  for (int idx = t; idx < 128; idx += nt){
    float sc = g[idx] * rsqrtf(vr[idx] + 1e-5f);
    bnsc[idx] = sc;
    bnsh[idx] = (b2[idx] - mn[idx]) * sc + be[idx];      // fold b2 into BN shift
  }
}

// ---------------- node GEMM: P = x@W2[0:128], Q = x@W2[128:256], f32, bf16 out ----------------
__global__ __launch_bounds__(256) void node_kernel(
    const float* __restrict__ x, const float* __restrict__ W2,
    unsigned short* __restrict__ P, unsigned short* __restrict__ Q, int N)
{
  __shared__ __align__(16) float xs[32 * 132];
  __shared__ __align__(16) float wsm[32 * 256];
  const int tid = threadIdx.x;
  const int nb = blockIdx.x * 32;
  #pragma unroll
  for (int i = 0; i < 4; i++){
    int idx = i * 1024 + tid * 4;
    int row = idx >> 7, col = idx & 127;
    int n = nb + row; if (n >= N) n = N - 1;
    *(f32x4*)&xs[row * 132 + col] = *(const f32x4*)&x[(size_t)n * 128 + col];
  }
  float acc[32];
  #pragma unroll
  for (int a = 0; a < 32; a++) acc[a] = 0.f;
  const int jg = tid & 7, nl = tid >> 3;
  for (int kc = 0; kc < 4; kc++){
    __syncthreads();
    #pragma unroll
    for (int i = 0; i < 8; i++){
      int idx = i * 1024 + tid * 4;
      int k = idx >> 8, j = idx & 255;
      const float* src = (j < 128) ? &W2[(size_t)(kc * 32 + k) * 128 + j]
                                   : &W2[(size_t)(128 + kc * 32 + k) * 128 + (j - 128)];
      *(f32x4*)&wsm[k * 256 + j] = *(const f32x4*)src;
    }
    __syncthreads();
    #pragma unroll 8
    for (int k = 0; k < 32; k++){
      float xv = xs[nl * 132 + kc * 32 + k];
      #pragma unroll
      for (int q = 0; q < 4; q++){
        f32x4 wp = *(const f32x4*)&wsm[k * 256 + jg * 4 + q * 32];
        f32x4 wq = *(const f32x4*)&wsm[k * 256 + 128 + jg * 4 + q * 32];
        #pragma unroll
        for (int ii = 0; ii < 4; ii++){
          acc[q * 4 + ii]      = fmaf(xv, wp[ii], acc[q * 4 + ii]);
          acc[16 + q * 4 + ii] = fmaf(xv, wq[ii], acc[16 + q * 4 + ii]);
        }
      }
    }
  }
  const int n = nb + nl;
  if (n < N){
    #pragma unroll
    for (int q = 0; q < 4; q++){
      uint2 v;
      v.x = (unsigned int)f2bf(acc[q*4+0]) | ((unsigned int)f2bf(acc[q*4+1]) << 16);
      v.y = (unsigned int)f2bf(acc[q*4+2]) | ((unsigned int)f2bf(acc[q*4+3]) << 16);
      *(uint2*)&P[(size_t)n * 128 + jg * 4 + q * 32] = v;
      v.x = (unsigned int)f2bf(acc[16+q*4+0]) | ((unsigned int)f2bf(acc[16+q*4+1]) << 16);
      v.y = (unsigned int)f2bf(acc[16+q*4+2]) | ((unsigned int)f2bf(acc[16+q*4+3]) << 16);
      *(uint2*)&Q[(size_t)n * 128 + jg * 4 + q * 32] = v;
    }
  }
}

// ---------------- fused edge kernel: 4 waves x 32 edges, MFMA chain ----------------
// P/Q gathered as 16B uint4 in stage-3 A-fragment layout, issued at kernel top.
// FIX vs r3: uint4 row index is kk*4 (kk*32 shorts), not kk*2 (kk*16 shorts).
__global__ __launch_bounds__(256, 2) void edge_kernel(
    const float* __restrict__ ea, const int* __restrict__ eidx,
    const unsigned short* __restrict__ P, const unsigned short* __restrict__ Q,
    const unsigned short* __restrict__ w1p, const unsigned short* __restrict__ w2cp,
    const unsigned short* __restrict__ w3p,
    const float* __restrict__ b1, const float* __restrict__ b3,
    const float* __restrict__ bnsc, const float* __restrict__ bnsh,
    float* __restrict__ y, int E, int N)
{
  __shared__ __align__(16) unsigned short w1f[4096];       // 8 KB
  __shared__ __align__(16) unsigned short w2cf[16384];     // 32 KB
  __shared__ __align__(16) unsigned short tch[4][32 * 136];// 34.8 KB (row stride 272B)
  __shared__ float cb1[128], cb3[128], cbs[128], cbh[128];

  const int tid = threadIdx.x;
  const int wid = tid >> 6, lane = tid & 63;
  const int r16 = lane & 15, hi = lane >> 4;
  const int e0 = (blockIdx.x * 4 + wid) * 32;
  unsigned short* myt = &tch[wid][0];

  // ---- early index loads + P/Q gathers (A-frag layout: 16B per (m,kk)) ----
  int ri[2], ci[2];
  #pragma unroll
  for (int m = 0; m < 2; m++){
    int e = e0 + m * 16 + r16; if (e >= E) e = E - 1;
    int r = eidx[e];     r = (r < 0) ? 0 : (r >= N ? N - 1 : r);
    int c = eidx[E + e]; c = (c < 0) ? 0 : (c >= N ? N - 1 : c);
    ri[m] = r; ci[m] = c;
  }
  uint4 pg[2][4], qg[2][4];
  #pragma unroll
  for (int m = 0; m < 2; m++){
    const uint4* pr = (const uint4*)(P + (size_t)ri[m] * 128 + hi * 8);
    const uint4* qr = (const uint4*)(Q + (size_t)ci[m] * 128 + hi * 8);
    #pragma unroll
    for (int kk = 0; kk < 4; kk++){
      pg[m][kk] = pr[kk * 4];     // cols kk*32 + hi*8 .. +7 (kk*4 uint4 = kk*32 shorts)
      qg[m][kk] = qr[kk * 4];
    }
  }

  // ---- ea A-fragments (row = l&15 -> edge, k = (l>>4)*8+i) ----
  s16x8 aF[2];
  #pragma unroll
  for (int m = 0; m < 2; m++){
    int e = e0 + m * 16 + r16; if (e >= E) e = E - 1;
    const f32x4* p = (const f32x4*)(ea + (size_t)e * 32 + hi * 8);
    f32x4 v0 = p[0], v1 = p[1];
    s16x8 t;
    t[0] = (short)f2bf(v0[0]); t[1] = (short)f2bf(v0[1]); t[2] = (short)f2bf(v0[2]); t[3] = (short)f2bf(v0[3]);
    t[4] = (short)f2bf(v1[0]); t[5] = (short)f2bf(v1[1]); t[6] = (short)f2bf(v1[2]); t[7] = (short)f2bf(v1[3]);
    aF[m] = t;
  }

  // ---- LDS weight staging ----
  {
    const uint4* s1 = (const uint4*)w1p; uint4* d1 = (uint4*)w1f;
    d1[tid] = s1[tid];
    d1[tid + 256] = s1[tid + 256];
    const uint4* s2 = (const uint4*)w2cp; uint4* d2 = (uint4*)w2cf;
    #pragma unroll
    for (int i = 0; i < 8; i++) d2[tid + i * 256] = s2[tid + i * 256];
    if (tid < 128){ cb1[tid] = b1[tid]; cb3[tid] = b3[tid]; cbs[tid] = bnsc[tid]; cbh[tid] = bnsh[tid]; }
  }
  __syncthreads();

  const s16x8* w1fv = (const s16x8*)w1f;
  const s16x8* w2cfv = (const s16x8*)w2cf;
  const f32x4 z = {0.f, 0.f, 0.f, 0.f};

  f32x4 c2[2][8];
  #pragma unroll
  for (int m = 0; m < 2; m++)
    #pragma unroll
    for (int n0 = 0; n0 < 8; n0++) c2[m][n0] = z;

  // ---- S1 (ea@W1 -> tanh -> t) chunked by K, feeding S2 (t@W2c) via LDS transpose ----
  #pragma unroll
  for (int kk = 0; kk < 4; kk++){
    f32x4 t1[2][2];
    #pragma unroll
    for (int j2 = 0; j2 < 2; j2++){
      s16x8 bF = w1fv[(kk * 2 + j2) * 64 + lane];
      t1[0][j2] = __builtin_amdgcn_mfma_f32_16x16x32_bf16(aF[0], bF, z, 0, 0, 0);
      t1[1][j2] = __builtin_amdgcn_mfma_f32_16x16x32_bf16(aF[1], bF, z, 0, 0, 0);
    }
    #pragma unroll
    for (int j2 = 0; j2 < 2; j2++){
      const int n0t = kk * 2 + j2;
      const float bb = cb1[n0t * 16 + r16];
      #pragma unroll
      for (int m = 0; m < 2; m++){
        #pragma unroll
        for (int r = 0; r < 4; r++){
          float tv = tanh_fast(t1[m][j2][r] + bb);
          myt[(m * 16 + hi * 4 + r) * 136 + j2 * 16 + r16] = f2bf(tv);
        }
      }
    }
    s16x8 a2[2];
    #pragma unroll
    for (int m = 0; m < 2; m++)
      a2[m] = *(const s16x8*)(myt + (m * 16 + r16) * 136 + hi * 8);
    #pragma unroll
    for (int n0 = 0; n0 < 8; n0++){
      s16x8 bF = w2cfv[(kk * 8 + n0) * 64 + lane];
      c2[0][n0] = __builtin_amdgcn_mfma_f32_16x16x32_bf16(a2[0], bF, c2[0][n0], 0, 0, 0);
      c2[1][n0] = __builtin_amdgcn_mfma_f32_16x16x32_bf16(a2[1], bF, c2[1][n0], 0, 0, 0);
    }
  }

  // ---- dump c2 (bf16) to LDS in C-layout (full 32x128 per wave) ----
  #pragma unroll
  for (int m = 0; m < 2; m++)
    #pragma unroll
    for (int n0 = 0; n0 < 8; n0++)
      #pragma unroll
      for (int r = 0; r < 4; r++)
        myt[(m * 16 + hi * 4 + r) * 136 + n0 * 16 + r16] = f2bf(c2[m][n0][r]);

  // ---- S3: h = relu(bn(c2 + P[row] + Q[col])) assembled in A-layout, @W3 ----
  f32x4 c3[2][8];
  #pragma unroll
  for (int m = 0; m < 2; m++)
    #pragma unroll
    for (int n0 = 0; n0 < 8; n0++) c3[m][n0] = z;

  const uint4* w3g = (const uint4*)w3p;
  #pragma unroll
  for (int kk = 0; kk < 4; kk++){
    f32x4 sc0 = *(const f32x4*)&cbs[kk * 32 + hi * 8];
    f32x4 sc1 = *(const f32x4*)&cbs[kk * 32 + hi * 8 + 4];
    f32x4 sh0 = *(const f32x4*)&cbh[kk * 32 + hi * 8];
    f32x4 sh1 = *(const f32x4*)&cbh[kk * 32 + hi * 8 + 4];
    s16x8 a3[2];
    #pragma unroll
    for (int m = 0; m < 2; m++){
      s16x8 ch = *(const s16x8*)(myt + (m * 16 + r16) * 136 + kk * 32 + hi * 8);
      union { uint4 u; unsigned short s[8]; } pu, qu;
      pu.u = pg[m][kk]; qu.u = qg[m][kk];
      s16x8 t;
      #pragma unroll
      for (int i = 0; i < 8; i++){
        float hv = bf2f((unsigned short)ch[i]) + bf2f(pu.s[i]) + bf2f(qu.s[i]);
        float sc = (i < 4) ? sc0[i] : sc1[i - 4];
        float sh = (i < 4) ? sh0[i] : sh1[i - 4];
        hv = fmaf(hv, sc, sh);
        hv = fmaxf(hv, 0.0f);
        t[i] = (short)f2bf(hv);
      }
      a3[m] = t;
    }
    #pragma unroll
    for (int n0 = 0; n0 < 8; n0++){
      uint4 bu = w3g[(kk * 8 + n0) * 64 + lane];
      union { uint4 u; s16x8 s; } cv; cv.u = bu;
      c3[0][n0] = __builtin_amdgcn_mfma_f32_16x16x32_bf16(a3[0], cv.s, c3[0][n0], 0, 0, 0);
      c3[1][n0] = __builtin_amdgcn_mfma_f32_16x16x32_bf16(a3[1], cv.s, c3[1][n0], 0, 0, 0);
    }
  }

  // ---- y = relu(c3 + b3) ----
  #pragma unroll
  for (int m = 0; m < 2; m++){
    #pragma unroll
    for (int r = 0; r < 4; r++){
      int em = e0 + m * 16 + hi * 4 + r;
      if (em < E){
        float* yp = y + (size_t)em * 128 + r16;
        #pragma unroll
        for (int n0 = 0; n0 < 8; n0++)
          yp[n0 * 16] = fmaxf(c3[m][n0][r] + cb3[n0 * 16 + r16], 0.0f);
      }
    }
  }
}

extern "C" void kernel_launch(void* const* d_in, const int* in_sizes, int n_in,
                              void* d_out, int out_size, void* d_ws, size_t ws_size,
                              hipStream_t stream)
{
  const float* x    = (const float*)d_in[0];
  const int*   eidx = (const int*)d_in[1];
  const float* ea   = (const float*)d_in[2];
  const float* W1   = (const float*)d_in[3];
  const float* b1   = (const float*)d_in[4];
  const float* W2   = (const float*)d_in[5];
  const float* b2   = (const float*)d_in[6];
  const float* bng  = (const float*)d_in[7];
  const float* bnb  = (const float*)d_in[8];
  const float* bnm  = (const float*)d_in[9];
  const float* bnv  = (const float*)d_in[10];
  const float* W3   = (const float*)d_in[11];
  const float* b3   = (const float*)d_in[12];
  float* y = (float*)d_out;
  const int N = in_sizes[0] / 128;
  const int E = in_sizes[2] / 32;

  // ws layout: P bf16 [N*128] | Q bf16 [N*128] | w1p[4096] | w2cp[16384] | w3p[16384] | bnsc[128] | bnsh[128]
  unsigned short* P    = (unsigned short*)d_ws;
  unsigned short* Qq   = P + (size_t)N * 128;
  unsigned short* w1p  = Qq + (size_t)N * 128;
  unsigned short* w2cp = w1p + 4096;
  unsigned short* w3p  = w2cp + 16384;
  float* bnsc = (float*)(w3p + 16384);
  float* bnsh = bnsc + 128;

  hipLaunchKernelGGL(prep_kernel, dim3(64), dim3(256), 0, stream,
                     W1, W2, W3, b2, bng, bnb, bnm, bnv, w1p, w2cp, w3p, bnsc, bnsh);
  hipLaunchKernelGGL(node_kernel, dim3((N + 31) / 32), dim3(256), 0, stream, x, W2, P, Qq, N);
  hipLaunchKernelGGL(edge_kernel, dim3((E + 127) / 128), dim3(256), 0, stream,
                     ea, eidx, P, Qq, w1p, w2cp, w3p, b1, b3, bnsc, bnsh, y, E, N);
}